// Round 21
// baseline (163.756 us; speedup 1.0000x reference)
//
#include <hip/hip_runtime.h>

typedef __attribute__((ext_vector_type(8))) short short8;
typedef __attribute__((ext_vector_type(4))) float f32x4;
typedef __attribute__((ext_vector_type(16))) float f32x16;
typedef __attribute__((ext_vector_type(4))) unsigned int u32x4;
typedef __attribute__((ext_vector_type(4))) unsigned short u16x4;
typedef unsigned int u32;
typedef unsigned short u16;

#define DEV static __device__ __forceinline__

DEV u16 f2bf(float f) {
  union { float f; u32 u; } c; c.f = f;
  u32 r = (c.u + 0x7fffu + ((c.u >> 16) & 1u)) >> 16;
  return (u16)r;
}
DEV float bf2f(u16 v) {
  union { u32 u; float f; } c; c.u = ((u32)v) << 16;
  return c.f;
}
DEV short8 pack8(float4 a, float4 b) {
  short8 r;
  r[0]=(short)f2bf(a.x); r[1]=(short)f2bf(a.y); r[2]=(short)f2bf(a.z); r[3]=(short)f2bf(a.w);
  r[4]=(short)f2bf(b.x); r[5]=(short)f2bf(b.y); r[6]=(short)f2bf(b.z); r[7]=(short)f2bf(b.w);
  return r;
}
DEV u32 cvtpk(float lo, float hi) {  // packed bf16 pair, RTNE
  u32 r;
  asm("v_cvt_pk_bf16_f32 %0, %1, %2" : "=v"(r) : "v"(lo), "v"(hi));
  return r;
}

// fast exp2: single v_exp_f32 (library exp2f carries range-check overhead)
#if __has_builtin(__builtin_amdgcn_exp2f)
DEV float fexp2(float x) { return __builtin_amdgcn_exp2f(x); }
#else
DEV float fexp2(float x) { return exp2f(x); }
#endif

DEV void glds16(const void* g, void* l) {
  __builtin_amdgcn_global_load_lds((const __attribute__((address_space(1))) u32*)g,
                                   (__attribute__((address_space(3))) u32*)l, 16, 0, 0);
}

DEV f32x16 mfma32(short8 a, short8 b, f32x16 c) {
  return __builtin_amdgcn_mfma_f32_32x32x16_bf16(a, b, c, 0, 0, 0);
}

constexpr int CDIM = 1024, TT = 2048, NH = 16, DK = 64;
// Q pre-scale: 1/sqrt(64) * log2(e)  (softmax runs in exp2 domain)
#define QSC 0.1803368801111601f

// ---------------- fp32 -> bf16 conversion, block-partitioned ---------------
__global__ void conv_bf16b(const float* __restrict__ X, const float* __restrict__ W1,
                           const float* __restrict__ W2, u16* __restrict__ Xb,
                           u16* __restrict__ W1b, u16* __restrict__ W2b) {
  const int bid = blockIdx.x;
  const float* s; u16* d; long base;
  if (bid < 1024)      { s = X;  d = Xb;  base = (long)bid * 1024; }
  else if (bid < 1408) { s = W1; d = W1b; base = (long)(bid - 1024) * 1024; }
  else                 { s = W2; d = W2b; base = (long)(bid - 1408) * 1024; }
#pragma unroll
  for (int i = 0; i < 4; ++i) {
    const long j = base + i * 256 + threadIdx.x;
    float4 a = ((const float4*)s)[2 * j];
    float4 b = ((const float4*)s)[2 * j + 1];
    ((short8*)d)[j] = pack8(a, b);
  }
}

// ---------------- QKV GEMM v9 (r18 winner): 128x128, 4 waves, swizzled ------
__global__ void qkv_gemm9(const u16* __restrict__ A, const u16* __restrict__ B,
                          const float* __restrict__ bias, u16* __restrict__ Qb,
                          u16* __restrict__ Kb, u16* __restrict__ VTb) {
  __shared__ u16 As[128][64];
  __shared__ u16 Bs[128][64];
  const int tid = threadIdx.x, lane = tid & 63, wv = tid >> 6;
  const int wr = wv >> 1, wc = wv & 1, lo = lane & 15, lg = lane >> 4;
  const int m0 = blockIdx.x * 128, n0 = blockIdx.y * 128;
  const int rin = lane >> 3, blk = lane & 7;
  const int r7 = lo & 7;

  f32x4 acc[4][4];
  const f32x4 fz = {0.f, 0.f, 0.f, 0.f};
#pragma unroll
  for (int i = 0; i < 4; ++i)
#pragma unroll
    for (int j = 0; j < 4; ++j) acc[i][j] = fz;

  const u16* ga = A + (size_t)(m0 + 32 * wv + rin) * CDIM + (blk ^ rin) * 8;
  const u16* gb = B + (size_t)(n0 + 32 * wv + rin) * CDIM + (blk ^ rin) * 8;

  for (int k0 = 0; k0 < CDIM; k0 += 64) {
#pragma unroll
    for (int i = 0; i < 4; ++i) glds16(ga + k0 + (size_t)(8 * i) * CDIM, &As[32 * wv + 8 * i][0]);
#pragma unroll
    for (int i = 0; i < 4; ++i) glds16(gb + k0 + (size_t)(8 * i) * CDIM, &Bs[32 * wv + 8 * i][0]);
    __syncthreads();
#pragma unroll
    for (int kk = 0; kk < 2; ++kk) {
      short8 af[4], bf[4];
#pragma unroll
      for (int mi = 0; mi < 4; ++mi)
        af[mi] = *(const short8*)&As[wr * 64 + mi * 16 + lo][(((kk * 4 + lg) ^ r7) * 8)];
#pragma unroll
      for (int ni = 0; ni < 4; ++ni)
        bf[ni] = *(const short8*)&Bs[wc * 64 + ni * 16 + lo][(((kk * 4 + lg) ^ r7) * 8)];
#pragma unroll
      for (int mi = 0; mi < 4; ++mi)
#pragma unroll
        for (int ni = 0; ni < 4; ++ni)
          acc[mi][ni] = __builtin_amdgcn_mfma_f32_16x16x32_bf16(af[mi], bf[ni], acc[mi][ni], 0, 0, 0);
    }
    __syncthreads();
  }

  // ---- scatter epilogue ----
#pragma unroll
  for (int ni = 0; ni < 4; ++ni) {
    const int o = n0 + wc * 64 + ni * 16 + lo;
    const float bv = bias[o];
    const int h = o / 192, rem = o - h * 192, which = rem >> 6, d = rem & 63;
#pragma unroll
    for (int mi = 0; mi < 4; ++mi) {
      const int mb = m0 + wr * 64 + mi * 16 + lg * 4;
      const int bb = mb >> 11, t0 = mb & 2047;
      const int bh = bb * NH + h;
      if (which == 2) {
        u16x4 pk;
#pragma unroll
        for (int r = 0; r < 4; ++r) pk[r] = f2bf(acc[mi][ni][r] + bv);
        *(u16x4*)&VTb[((size_t)bh * DK + d) * TT + t0] = pk;
      } else if (which == 1) {
#pragma unroll
        for (int r = 0; r < 4; ++r)
          Kb[((size_t)bh * TT + t0 + r) * DK + d] = f2bf(acc[mi][ni][r] + bv);
      } else {
#pragma unroll
        for (int r = 0; r < 4; ++r)
          Qb[((size_t)bh * TT + t0 + r) * DK + d] = f2bf((acc[mi][ni][r] + bv) * QSC);
      }
    }
  }
}

// ---------------- Flash attention v12: single-buffer K/V, natural occupancy -
// LDS 16.4KB -> HW residency 8 blocks/CU at VGPR~64 (32 waves/CU); TLP hides
// the per-tile stage latency (r19's idea done right: no VGPR strangling).
__global__ void __launch_bounds__(256)
attn12(const u16* __restrict__ Qb, const u16* __restrict__ Kb,
       const u16* __restrict__ VTb, u16* __restrict__ PA, u16* __restrict__ PB,
       float* __restrict__ ML) {
  __shared__ u16 Kls[64][64];
  __shared__ u16 Vls[64][64];
  const int tid = threadIdx.x, lane = tid & 63, wv = tid >> 6;
  const int lq = lane & 31, h = lane >> 5;
  const int id = blockIdx.x;
  const int w = (id & 7) * 128 + (id >> 3);  // logical work index, XCD-chunked
  const int bh = w >> 4;                     // bh clustered per XCD
  const int pj = w & 7;                      // pair index
  const int sp = (w >> 3) & 1;               // kv parity
  const int bb = bh >> 4, head = bh & 15;
  const u16* Qp = Qb + (size_t)bh * TT * DK;
  const u16* Kp = Kb + (size_t)bh * TT * DK;
  const u16* Vp = VTb + (size_t)bh * DK * TT;
  const int rin = lane >> 3, blk = lane & 7;
  u16* PO = sp ? PB : PA;

  const u16* kga = Kp + (size_t)(wv * 16 + rin) * DK + (blk ^ rin) * 8;
  const u16* vga = Vp + (size_t)(wv * 16 + rin) * TT + (blk ^ rin) * 8;
  u16* kls0 = &Kls[wv * 16][0];
  u16* vls0 = &Vls[wv * 16][0];

#define STAGE12(kvt_)                                                       \
  {                                                                         \
    glds16(kga + (size_t)(kvt_) * 4096, kls0);                              \
    glds16(kga + (size_t)(kvt_) * 4096 + 512, kls0 + 512);                  \
    glds16(vga + (size_t)(kvt_) * 64, vls0);                                \
    glds16(vga + (size_t)(kvt_) * 64 + 8 * TT, vls0 + 512);                 \
  }

  for (int pi = 0; pi < 2; ++pi) {
    const int qtile = pi ? (15 - pj) : pj;
    const int q0w = qtile * 128 + wv * 32;
    const int qrow = q0w + lq;

    short8 qw[4];
#pragma unroll
    for (int kk = 0; kk < 4; ++kk)
      qw[kk] = *(const short8*)&Qp[(size_t)qrow * DK + kk * 16 + h * 8];

    f32x16 oa0, oa1;
#pragma unroll
    for (int r = 0; r < 16; ++r) { oa0[r] = 0.f; oa1[r] = 0.f; }
    float l_s = 0.f;

    const int nt = 2 * qtile + 2;
    for (int kvt = sp; kvt < nt; kvt += 2) {
      const int kv0 = kvt * 64;
      STAGE12(kvt);
      asm volatile("s_waitcnt vmcnt(0)" ::: "memory");
      __builtin_amdgcn_s_barrier();
      {
        f32x16 s0, s1;
#pragma unroll
        for (int r = 0; r < 16; ++r) { s0[r] = 0.f; s1[r] = 0.f; }
        __builtin_amdgcn_s_setprio(1);
#pragma unroll
        for (int kk = 0; kk < 4; ++kk) {
          const short8 kf0 = *(const short8*)&Kls[lq][(((2 * kk + h) ^ (lq & 7)) * 8)];
          const short8 kf1 = *(const short8*)&Kls[32 + lq][(((2 * kk + h) ^ (lq & 7)) * 8)];
          s0 = mfma32(kf0, qw[kk], s0);
          s1 = mfma32(kf1, qw[kk], s1);
        }
        __builtin_amdgcn_s_setprio(0);
        const bool diag = (kv0 + 63 > q0w);
        if (diag) {
          const int lim = qrow - kv0 - 4 * h;
#pragma unroll
          for (int r = 0; r < 16; ++r) {
            const int kl = (r & 3) + 8 * (r >> 2);
            s0[r] = (kl <= lim) ? s0[r] : -1e30f;
            s1[r] = (kl + 32 <= lim) ? s1[r] : -1e30f;
          }
        }
        float rsa = 0.f, rsb = 0.f, rsc = 0.f, rsd = 0.f;
#pragma unroll
        for (int r = 0; r < 16; r += 4) {
          const float a0 = fexp2(s0[r]),     a1 = fexp2(s1[r]);
          const float b0 = fexp2(s0[r + 1]), b1 = fexp2(s1[r + 1]);
          const float c0 = fexp2(s0[r + 2]), c1 = fexp2(s1[r + 2]);
          const float d0 = fexp2(s0[r + 3]), d1 = fexp2(s1[r + 3]);
          s0[r] = a0; s1[r] = a1; s0[r + 1] = b0; s1[r + 1] = b1;
          s0[r + 2] = c0; s1[r + 2] = c1; s0[r + 3] = d0; s1[r + 3] = d1;
          rsa += a0 + a1; rsb += b0 + b1; rsc += c0 + c1; rsd += d0 + d1;
        }
        float rs = (rsa + rsb) + (rsc + rsd);
        rs += __shfl_xor(rs, 32);
        l_s += rs;
#pragma unroll
        for (int s = 0; s < 2; ++s) {
          u32 C[8];
#pragma unroll
          for (int j = 0; j < 8; ++j)
            C[j] = s ? cvtpk(s1[2 * j], s1[2 * j + 1]) : cvtpk(s0[2 * j], s0[2 * j + 1]);
#pragma unroll
          for (int b = 0; b < 2; ++b) {
            const int o = 4 * b;
            const u32 D1 = h ? C[o + 0] : C[o + 2];
            const u32 D2 = h ? C[o + 1] : C[o + 3];
            const u32 R1 = __shfl_xor(D1, 32);
            const u32 R2 = __shfl_xor(D2, 32);
            union { u32x4 w; short8 s8; } pa;
            pa.w[0] = h ? R1 : C[o + 0];
            pa.w[1] = h ? R2 : C[o + 1];
            pa.w[2] = h ? C[o + 2] : R1;
            pa.w[3] = h ? C[o + 3] : R2;
            const int ks = 2 * s + b;
            const short8 vb0 = *(const short8*)&Vls[lq][(((2 * ks + h) ^ (lq & 7)) * 8)];
            const short8 vb1 = *(const short8*)&Vls[32 + lq][(((2 * ks + h) ^ (lq & 7)) * 8)];
            __builtin_amdgcn_s_setprio(1);
            oa0 = mfma32(pa.s8, vb0, oa0);
            oa1 = mfma32(pa.s8, vb1, oa1);
            __builtin_amdgcn_s_setprio(0);
          }
        }
      }
      __syncthreads();
    }

#pragma unroll
    for (int r = 0; r < 16; ++r) {
      const int t = q0w + (r & 3) + 8 * (r >> 2) + 4 * h;
      const size_t rowb = ((size_t)(bb * TT + t)) * CDIM + head * DK;
      PO[rowb + lq] = f2bf(oa0[r]);
      PO[rowb + 32 + lq] = f2bf(oa1[r]);
    }
    if (h == 0) ML[((size_t)(sp * 64 + bh) << 11) + qrow] = l_s;
    __syncthreads();
  }
#undef STAGE12
}

// ---------------- merge of the two kv-parity partials ----------------------
__global__ void attn_merge(const u16* PA, const u16* PB,
                           const float* __restrict__ ML, u16* Ctx) {
  const int row = blockIdx.x;  // b*2048 + t
  const int b = row >> 11, t = row & 2047;
  const int c = threadIdx.x * 4;
  const int head = c >> 6;
  const int bh = b * NH + head;
  const float lA = ML[((size_t)bh << 11) + t];
  const float lB = ML[((size_t)(64 + bh) << 11) + t];
  const float il = 1.0f / (lA + lB);
  const size_t idx = ((size_t)row) * CDIM + c;
  u16x4 pa = *(const u16x4*)&PA[idx];
  u16x4 pb = *(const u16x4*)&PB[idx];
  u16x4 o;
#pragma unroll
  for (int e = 0; e < 4; ++e) o[e] = f2bf((bf2f(pa[e]) + bf2f(pb[e])) * il);
  *(u16x4*)&Ctx[idx] = o;
}

// ---------------- Output GEMM v4: m97 structure + proven LDS swizzle --------
__global__ void out_gemm4(const u16* __restrict__ A, const u16* __restrict__ B,
                          const float* __restrict__ bias, float* __restrict__ Out) {
  __shared__ u16 As[128][64];
  __shared__ u16 Bs[128][64];
  const int tid = threadIdx.x, lane = tid & 63, wv = tid >> 6;
  const int wr = wv >> 1, wc = wv & 1, lo = lane & 15, lg = lane >> 4;
  const int m0 = blockIdx.x * 128, n0 = blockIdx.y * 128;
  const int rin = lane >> 3, blk = lane & 7;
  const int r7 = lo & 7;

  f32x4 acc[4][4];
  const f32x4 fz = {0.f, 0.f, 0.f, 0.f};
#pragma unroll
  for (int i = 0; i < 4; ++i)
#pragma unroll
    for (int j = 0; j < 4; ++j) acc[i][j] = fz;

  const u16* ga = A + (size_t)(m0 + 32 * wv + rin) * CDIM + (blk ^ rin) * 8;
  const u16* gb = B + (size_t)(n0 + 32 * wv + rin) * CDIM + (blk ^ rin) * 8;

  for (int k0 = 0; k0 < CDIM; k0 += 64) {
#pragma unroll
    for (int i = 0; i < 4; ++i) glds16(ga + k0 + (size_t)(8 * i) * CDIM, &As[32 * wv + 8 * i][0]);
#pragma unroll
    for (int i = 0; i < 4; ++i) glds16(gb + k0 + (size_t)(8 * i) * CDIM, &Bs[32 * wv + 8 * i][0]);
    __syncthreads();
#pragma unroll
    for (int kk = 0; kk < 2; ++kk) {
      short8 af[4], bf[4];
#pragma unroll
      for (int mi = 0; mi < 4; ++mi)
        af[mi] = *(const short8*)&As[wr * 64 + mi * 16 + lo][(((kk * 4 + lg) ^ r7) * 8)];
#pragma unroll
      for (int ni = 0; ni < 4; ++ni)
        bf[ni] = *(const short8*)&Bs[wc * 64 + ni * 16 + lo][(((kk * 4 + lg) ^ r7) * 8)];
#pragma unroll
      for (int mi = 0; mi < 4; ++mi)
#pragma unroll
        for (int ni = 0; ni < 4; ++ni)
          acc[mi][ni] = __builtin_amdgcn_mfma_f32_16x16x32_bf16(af[mi], bf[ni], acc[mi][ni], 0, 0, 0);
    }
    __syncthreads();
  }

#pragma unroll
  for (int ni = 0; ni < 4; ++ni) {
    const int o = n0 + wc * 64 + ni * 16 + lo;
    const float bv = bias[o];
#pragma unroll
    for (int mi = 0; mi < 4; ++mi)
#pragma unroll
      for (int r = 0; r < 4; ++r)
        Out[(size_t)(m0 + wr * 64 + mi * 16 + lg * 4 + r) * CDIM + o] = acc[mi][ni][r] + bv;
  }
}

extern "C" void kernel_launch(void* const* d_in, const int* in_sizes, int n_in,
                              void* d_out, int out_size, void* d_ws, size_t ws_size,
                              hipStream_t stream) {
  const float* X = (const float*)d_in[0];
  const float* Wqkv = (const float*)d_in[1];
  const float* bqkv = (const float*)d_in[2];
  const float* Wout = (const float*)d_in[3];
  const float* bout = (const float*)d_in[4];
  float* Out = (float*)d_out;

  u16* Xb  = (u16*)d_ws;              // 8,388,608 u16 (reused as PB after qkv)
  u16* W1b = Xb + 8388608;            // 3,145,728 u16 (reused as ML after qkv)
  u16* W2b = W1b + 3145728;           // 1,048,576
  u16* Qb  = W2b + 1048576;           // 8,388,608 (pre-scaled by QSC)
  u16* Kb  = Qb + 8388608;            // 8,388,608
  u16* VTb = Kb + 8388608;            // 8,388,608 (transposed: [bh][d][t])
  u16* Ctx = VTb + 8388608;           // 8,388,608 (PA partial, then merged in-place)

  conv_bf16b<<<1536, 256, 0, stream>>>(X, Wqkv, Wout, Xb, W1b, W2b);
  qkv_gemm9<<<dim3(64, 24), 256, 0, stream>>>(Xb, W1b, bqkv, Qb, Kb, VTb);
  attn12<<<dim3(1024), 256, 0, stream>>>(Qb, Kb, VTb, Ctx, Xb, (float*)W1b);
  attn_merge<<<8192, 256, 0, stream>>>(Ctx, Xb, (const float*)W1b, Ctx);
  out_gemm4<<<dim3(64, 8), 256, 0, stream>>>(Ctx, W2b, bout, Out);
}

// Round 22
// 150.753 us; speedup vs baseline: 1.0862x; 1.0862x over previous
//
#include <hip/hip_runtime.h>

typedef __attribute__((ext_vector_type(8))) short short8;
typedef __attribute__((ext_vector_type(4))) float f32x4;
typedef __attribute__((ext_vector_type(16))) float f32x16;
typedef __attribute__((ext_vector_type(4))) unsigned int u32x4;
typedef __attribute__((ext_vector_type(4))) unsigned short u16x4;
typedef unsigned int u32;
typedef unsigned short u16;

#define DEV static __device__ __forceinline__

DEV u16 f2bf(float f) {
  union { float f; u32 u; } c; c.f = f;
  u32 r = (c.u + 0x7fffu + ((c.u >> 16) & 1u)) >> 16;
  return (u16)r;
}
DEV float bf2f(u16 v) {
  union { u32 u; float f; } c; c.u = ((u32)v) << 16;
  return c.f;
}
DEV short8 pack8(float4 a, float4 b) {
  short8 r;
  r[0]=(short)f2bf(a.x); r[1]=(short)f2bf(a.y); r[2]=(short)f2bf(a.z); r[3]=(short)f2bf(a.w);
  r[4]=(short)f2bf(b.x); r[5]=(short)f2bf(b.y); r[6]=(short)f2bf(b.z); r[7]=(short)f2bf(b.w);
  return r;
}
DEV u32 cvtpk(float lo, float hi) {  // packed bf16 pair, RTNE
  u32 r;
  asm("v_cvt_pk_bf16_f32 %0, %1, %2" : "=v"(r) : "v"(lo), "v"(hi));
  return r;
}

// fast exp2: single v_exp_f32 (library exp2f carries range-check overhead)
#if __has_builtin(__builtin_amdgcn_exp2f)
DEV float fexp2(float x) { return __builtin_amdgcn_exp2f(x); }
#else
DEV float fexp2(float x) { return exp2f(x); }
#endif

DEV void glds16(const void* g, void* l) {
  __builtin_amdgcn_global_load_lds((const __attribute__((address_space(1))) u32*)g,
                                   (__attribute__((address_space(3))) u32*)l, 16, 0, 0);
}

DEV f32x16 mfma32(short8 a, short8 b, f32x16 c) {
  return __builtin_amdgcn_mfma_f32_32x32x16_bf16(a, b, c, 0, 0, 0);
}

constexpr int CDIM = 1024, TT = 2048, NH = 16, DK = 64;
// Q pre-scale: 1/sqrt(64) * log2(e)  (softmax runs in exp2 domain)
#define QSC 0.1803368801111601f

// ---------------- fp32 -> bf16 conversion, block-partitioned ---------------
__global__ void conv_bf16b(const float* __restrict__ X, const float* __restrict__ W1,
                           const float* __restrict__ W2, u16* __restrict__ Xb,
                           u16* __restrict__ W1b, u16* __restrict__ W2b) {
  const int bid = blockIdx.x;
  const float* s; u16* d; long base;
  if (bid < 1024)      { s = X;  d = Xb;  base = (long)bid * 1024; }
  else if (bid < 1408) { s = W1; d = W1b; base = (long)(bid - 1024) * 1024; }
  else                 { s = W2; d = W2b; base = (long)(bid - 1408) * 1024; }
#pragma unroll
  for (int i = 0; i < 4; ++i) {
    const long j = base + i * 256 + threadIdx.x;
    float4 a = ((const float4*)s)[2 * j];
    float4 b = ((const float4*)s)[2 * j + 1];
    ((short8*)d)[j] = pack8(a, b);
  }
}

// ---------------- QKV GEMM v9 (r18 winner): 128x128, 4 waves, swizzled ------
__global__ void qkv_gemm9(const u16* __restrict__ A, const u16* __restrict__ B,
                          const float* __restrict__ bias, u16* __restrict__ Qb,
                          u16* __restrict__ Kb, u16* __restrict__ VTb) {
  __shared__ u16 As[128][64];
  __shared__ u16 Bs[128][64];
  const int tid = threadIdx.x, lane = tid & 63, wv = tid >> 6;
  const int wr = wv >> 1, wc = wv & 1, lo = lane & 15, lg = lane >> 4;
  const int m0 = blockIdx.x * 128, n0 = blockIdx.y * 128;
  const int rin = lane >> 3, blk = lane & 7;
  const int r7 = lo & 7;

  f32x4 acc[4][4];
  const f32x4 fz = {0.f, 0.f, 0.f, 0.f};
#pragma unroll
  for (int i = 0; i < 4; ++i)
#pragma unroll
    for (int j = 0; j < 4; ++j) acc[i][j] = fz;

  const u16* ga = A + (size_t)(m0 + 32 * wv + rin) * CDIM + (blk ^ rin) * 8;
  const u16* gb = B + (size_t)(n0 + 32 * wv + rin) * CDIM + (blk ^ rin) * 8;

  for (int k0 = 0; k0 < CDIM; k0 += 64) {
#pragma unroll
    for (int i = 0; i < 4; ++i) glds16(ga + k0 + (size_t)(8 * i) * CDIM, &As[32 * wv + 8 * i][0]);
#pragma unroll
    for (int i = 0; i < 4; ++i) glds16(gb + k0 + (size_t)(8 * i) * CDIM, &Bs[32 * wv + 8 * i][0]);
    __syncthreads();
#pragma unroll
    for (int kk = 0; kk < 2; ++kk) {
      short8 af[4], bf[4];
#pragma unroll
      for (int mi = 0; mi < 4; ++mi)
        af[mi] = *(const short8*)&As[wr * 64 + mi * 16 + lo][(((kk * 4 + lg) ^ r7) * 8)];
#pragma unroll
      for (int ni = 0; ni < 4; ++ni)
        bf[ni] = *(const short8*)&Bs[wc * 64 + ni * 16 + lo][(((kk * 4 + lg) ^ r7) * 8)];
#pragma unroll
      for (int mi = 0; mi < 4; ++mi)
#pragma unroll
        for (int ni = 0; ni < 4; ++ni)
          acc[mi][ni] = __builtin_amdgcn_mfma_f32_16x16x32_bf16(af[mi], bf[ni], acc[mi][ni], 0, 0, 0);
    }
    __syncthreads();
  }

  // ---- scatter epilogue ----
#pragma unroll
  for (int ni = 0; ni < 4; ++ni) {
    const int o = n0 + wc * 64 + ni * 16 + lo;
    const float bv = bias[o];
    const int h = o / 192, rem = o - h * 192, which = rem >> 6, d = rem & 63;
#pragma unroll
    for (int mi = 0; mi < 4; ++mi) {
      const int mb = m0 + wr * 64 + mi * 16 + lg * 4;
      const int bb = mb >> 11, t0 = mb & 2047;
      const int bh = bb * NH + h;
      if (which == 2) {
        u16x4 pk;
#pragma unroll
        for (int r = 0; r < 4; ++r) pk[r] = f2bf(acc[mi][ni][r] + bv);
        *(u16x4*)&VTb[((size_t)bh * DK + d) * TT + t0] = pk;
      } else if (which == 1) {
#pragma unroll
        for (int r = 0; r < 4; ++r)
          Kb[((size_t)bh * TT + t0 + r) * DK + d] = f2bf(acc[mi][ni][r] + bv);
      } else {
#pragma unroll
        for (int r = 0; r < 4; ++r)
          Qb[((size_t)bh * TT + t0 + r) * DK + d] = f2bf((acc[mi][ni][r] + bv) * QSC);
      }
    }
  }
}

// ---------------- Flash attention v10 (r18 winner): no-max, 4 blocks/CU -----
__global__ void __launch_bounds__(256, 4)
attn10(const u16* __restrict__ Qb, const u16* __restrict__ Kb,
       const u16* __restrict__ VTb, u16* __restrict__ PA, u16* __restrict__ PB,
       float* __restrict__ ML) {
  __shared__ u16 Kls[2][64][64];
  __shared__ u16 Vls[2][64][64];
  const int tid = threadIdx.x, lane = tid & 63, wv = tid >> 6;
  const int lq = lane & 31, h = lane >> 5;
  const int id = blockIdx.x;
  const int w = (id & 7) * 128 + (id >> 3);  // logical work index, XCD-chunked
  const int bh = w >> 4;                     // 8 bh per XCD
  const int pj = w & 7;                      // pair index
  const int sp = (w >> 3) & 1;               // kv parity
  const int bb = bh >> 4, head = bh & 15;
  const u16* Qp = Qb + (size_t)bh * TT * DK;
  const u16* Kp = Kb + (size_t)bh * TT * DK;
  const u16* Vp = VTb + (size_t)bh * DK * TT;
  const int rin = lane >> 3, blk = lane & 7;
  u16* PO = sp ? PB : PA;

  const u16* kga = Kp + (size_t)(wv * 16 + rin) * DK + (blk ^ rin) * 8;
  const u16* vga = Vp + (size_t)(wv * 16 + rin) * TT + (blk ^ rin) * 8;
  u16* kls0 = &Kls[0][wv * 16][0];
  u16* vls0 = &Vls[0][wv * 16][0];
  const int lds_half = 64 * 64;  // u16 elems between buf 0 and 1

#define STAGE10(bufi, kvt_)                                                 \
  {                                                                         \
    const int o_ = (bufi) * lds_half;                                       \
    glds16(kga + (size_t)(kvt_) * 4096, kls0 + o_);                         \
    glds16(kga + (size_t)(kvt_) * 4096 + 512, kls0 + o_ + 512);             \
    glds16(vga + (size_t)(kvt_) * 64, vls0 + o_);                           \
    glds16(vga + (size_t)(kvt_) * 64 + 8 * TT, vls0 + o_ + 512);            \
  }

  for (int pi = 0; pi < 2; ++pi) {
    const int qtile = pi ? (15 - pj) : pj;
    const int q0w = qtile * 128 + wv * 32;
    const int qrow = q0w + lq;

    short8 qw[4];
#pragma unroll
    for (int kk = 0; kk < 4; ++kk)
      qw[kk] = *(const short8*)&Qp[(size_t)qrow * DK + kk * 16 + h * 8];

    f32x16 oa0, oa1;
#pragma unroll
    for (int r = 0; r < 16; ++r) { oa0[r] = 0.f; oa1[r] = 0.f; }
    float l_s = 0.f;

    const int nt = 2 * qtile + 2;
    STAGE10(0, sp);
    __syncthreads();
    int buf = 0;
    for (int kvt = sp; kvt < nt; kvt += 2) {
      const int kv0 = kvt * 64;
      if (kvt + 2 < nt) STAGE10(buf ^ 1, kvt + 2);
      if (kv0 <= q0w + 31) {
        f32x16 s0, s1;
#pragma unroll
        for (int r = 0; r < 16; ++r) { s0[r] = 0.f; s1[r] = 0.f; }
        __builtin_amdgcn_s_setprio(1);
#pragma unroll
        for (int kk = 0; kk < 4; ++kk) {
          const short8 kf0 = *(const short8*)&Kls[buf][lq][(((2 * kk + h) ^ (lq & 7)) * 8)];
          const short8 kf1 = *(const short8*)&Kls[buf][32 + lq][(((2 * kk + h) ^ (lq & 7)) * 8)];
          s0 = mfma32(kf0, qw[kk], s0);
          s1 = mfma32(kf1, qw[kk], s1);
        }
        __builtin_amdgcn_s_setprio(0);
        const bool diag = (kv0 + 63 > q0w);
        if (diag) {
          const int lim = qrow - kv0 - 4 * h;
#pragma unroll
          for (int r = 0; r < 16; ++r) {
            const int kl = (r & 3) + 8 * (r >> 2);
            s0[r] = (kl <= lim) ? s0[r] : -1e30f;
            s1[r] = (kl + 32 <= lim) ? s1[r] : -1e30f;
          }
        }
        float rsa = 0.f, rsb = 0.f, rsc = 0.f, rsd = 0.f;
#pragma unroll
        for (int r = 0; r < 16; r += 4) {
          const float a0 = fexp2(s0[r]),     a1 = fexp2(s1[r]);
          const float b0 = fexp2(s0[r + 1]), b1 = fexp2(s1[r + 1]);
          const float c0 = fexp2(s0[r + 2]), c1 = fexp2(s1[r + 2]);
          const float d0 = fexp2(s0[r + 3]), d1 = fexp2(s1[r + 3]);
          s0[r] = a0; s1[r] = a1; s0[r + 1] = b0; s1[r + 1] = b1;
          s0[r + 2] = c0; s1[r + 2] = c1; s0[r + 3] = d0; s1[r + 3] = d1;
          rsa += a0 + a1; rsb += b0 + b1; rsc += c0 + c1; rsd += d0 + d1;
        }
        float rs = (rsa + rsb) + (rsc + rsd);
        rs += __shfl_xor(rs, 32);
        l_s += rs;
#pragma unroll
        for (int s = 0; s < 2; ++s) {
          u32 C[8];
#pragma unroll
          for (int j = 0; j < 8; ++j)
            C[j] = s ? cvtpk(s1[2 * j], s1[2 * j + 1]) : cvtpk(s0[2 * j], s0[2 * j + 1]);
#pragma unroll
          for (int b = 0; b < 2; ++b) {
            const int o = 4 * b;
            const u32 D1 = h ? C[o + 0] : C[o + 2];
            const u32 D2 = h ? C[o + 1] : C[o + 3];
            const u32 R1 = __shfl_xor(D1, 32);
            const u32 R2 = __shfl_xor(D2, 32);
            union { u32x4 w; short8 s8; } pa;
            pa.w[0] = h ? R1 : C[o + 0];
            pa.w[1] = h ? R2 : C[o + 1];
            pa.w[2] = h ? C[o + 2] : R1;
            pa.w[3] = h ? C[o + 3] : R2;
            const int ks = 2 * s + b;
            const short8 vb0 = *(const short8*)&Vls[buf][lq][(((2 * ks + h) ^ (lq & 7)) * 8)];
            const short8 vb1 = *(const short8*)&Vls[buf][32 + lq][(((2 * ks + h) ^ (lq & 7)) * 8)];
            __builtin_amdgcn_s_setprio(1);
            oa0 = mfma32(pa.s8, vb0, oa0);
            oa1 = mfma32(pa.s8, vb1, oa1);
            __builtin_amdgcn_s_setprio(0);
          }
        }
      }
      __syncthreads();
      buf ^= 1;
    }

#pragma unroll
    for (int r = 0; r < 16; ++r) {
      const int t = q0w + (r & 3) + 8 * (r >> 2) + 4 * h;
      const size_t rowb = ((size_t)(bb * TT + t)) * CDIM + head * DK;
      PO[rowb + lq] = f2bf(oa0[r]);
      PO[rowb + 32 + lq] = f2bf(oa1[r]);
    }
    if (h == 0) ML[((size_t)(sp * 64 + bh) << 11) + qrow] = l_s;
    __syncthreads();
  }
#undef STAGE10
}

// ---------------- merge of the two kv-parity partials ----------------------
__global__ void attn_merge(const u16* PA, const u16* PB,
                           const float* __restrict__ ML, u16* Ctx) {
  const int row = blockIdx.x;  // b*2048 + t
  const int b = row >> 11, t = row & 2047;
  const int c = threadIdx.x * 4;
  const int head = c >> 6;
  const int bh = b * NH + head;
  const float lA = ML[((size_t)bh << 11) + t];
  const float lB = ML[((size_t)(64 + bh) << 11) + t];
  const float il = 1.0f / (lA + lB);
  const size_t idx = ((size_t)row) * CDIM + c;
  u16x4 pa = *(const u16x4*)&PA[idx];
  u16x4 pb = *(const u16x4*)&PB[idx];
  u16x4 o;
#pragma unroll
  for (int e = 0; e < 4; ++e) o[e] = f2bf((bf2f(pa[e]) + bf2f(pb[e])) * il);
  *(u16x4*)&Ctx[idx] = o;
}

// ---------------- Output GEMM v4: m97 structure + proven LDS swizzle --------
__global__ void out_gemm4(const u16* __restrict__ A, const u16* __restrict__ B,
                          const float* __restrict__ bias, float* __restrict__ Out) {
  __shared__ u16 As[128][64];
  __shared__ u16 Bs[128][64];
  const int tid = threadIdx.x, lane = tid & 63, wv = tid >> 6;
  const int wr = wv >> 1, wc = wv & 1, lo = lane & 15, lg = lane >> 4;
  const int m0 = blockIdx.x * 128, n0 = blockIdx.y * 128;
  const int rin = lane >> 3, blk = lane & 7;
  const int r7 = lo & 7;

  f32x4 acc[4][4];
  const f32x4 fz = {0.f, 0.f, 0.f, 0.f};
#pragma unroll
  for (int i = 0; i < 4; ++i)
#pragma unroll
    for (int j = 0; j < 4; ++j) acc[i][j] = fz;

  const u16* ga = A + (size_t)(m0 + 32 * wv + rin) * CDIM + (blk ^ rin) * 8;
  const u16* gb = B + (size_t)(n0 + 32 * wv + rin) * CDIM + (blk ^ rin) * 8;

  for (int k0 = 0; k0 < CDIM; k0 += 64) {
#pragma unroll
    for (int i = 0; i < 4; ++i) glds16(ga + k0 + (size_t)(8 * i) * CDIM, &As[32 * wv + 8 * i][0]);
#pragma unroll
    for (int i = 0; i < 4; ++i) glds16(gb + k0 + (size_t)(8 * i) * CDIM, &Bs[32 * wv + 8 * i][0]);
    __syncthreads();
#pragma unroll
    for (int kk = 0; kk < 2; ++kk) {
      short8 af[4], bf[4];
#pragma unroll
      for (int mi = 0; mi < 4; ++mi)
        af[mi] = *(const short8*)&As[wr * 64 + mi * 16 + lo][(((kk * 4 + lg) ^ r7) * 8)];
#pragma unroll
      for (int ni = 0; ni < 4; ++ni)
        bf[ni] = *(const short8*)&Bs[wc * 64 + ni * 16 + lo][(((kk * 4 + lg) ^ r7) * 8)];
#pragma unroll
      for (int mi = 0; mi < 4; ++mi)
#pragma unroll
        for (int ni = 0; ni < 4; ++ni)
          acc[mi][ni] = __builtin_amdgcn_mfma_f32_16x16x32_bf16(af[mi], bf[ni], acc[mi][ni], 0, 0, 0);
    }
    __syncthreads();
  }

#pragma unroll
  for (int ni = 0; ni < 4; ++ni) {
    const int o = n0 + wc * 64 + ni * 16 + lo;
    const float bv = bias[o];
#pragma unroll
    for (int mi = 0; mi < 4; ++mi)
#pragma unroll
      for (int r = 0; r < 4; ++r)
        Out[(size_t)(m0 + wr * 64 + mi * 16 + lg * 4 + r) * CDIM + o] = acc[mi][ni][r] + bv;
  }
}

extern "C" void kernel_launch(void* const* d_in, const int* in_sizes, int n_in,
                              void* d_out, int out_size, void* d_ws, size_t ws_size,
                              hipStream_t stream) {
  const float* X = (const float*)d_in[0];
  const float* Wqkv = (const float*)d_in[1];
  const float* bqkv = (const float*)d_in[2];
  const float* Wout = (const float*)d_in[3];
  const float* bout = (const float*)d_in[4];
  float* Out = (float*)d_out;

  u16* Xb  = (u16*)d_ws;              // 8,388,608 u16 (reused as PB after qkv)
  u16* W1b = Xb + 8388608;            // 3,145,728 u16 (reused as ML after qkv)
  u16* W2b = W1b + 3145728;           // 1,048,576
  u16* Qb  = W2b + 1048576;           // 8,388,608 (pre-scaled by QSC)
  u16* Kb  = Qb + 8388608;            // 8,388,608
  u16* VTb = Kb + 8388608;            // 8,388,608 (transposed: [bh][d][t])
  u16* Ctx = VTb + 8388608;           // 8,388,608 (PA partial, then merged in-place)

  conv_bf16b<<<1536, 256, 0, stream>>>(X, Wqkv, Wout, Xb, W1b, W2b);
  qkv_gemm9<<<dim3(64, 24), 256, 0, stream>>>(Xb, W1b, bqkv, Qb, Kb, VTb);
  attn10<<<dim3(1024), 256, 0, stream>>>(Qb, Kb, VTb, Ctx, Xb, (float*)W1b);
  attn_merge<<<8192, 256, 0, stream>>>(Ctx, Xb, (const float*)W1b, Ctx);
  out_gemm4<<<dim3(64, 8), 256, 0, stream>>>(Ctx, W2b, bout, Out);
}

// Round 23
// 148.357 us; speedup vs baseline: 1.1038x; 1.0161x over previous
//
#include <hip/hip_runtime.h>

typedef __attribute__((ext_vector_type(8))) short short8;
typedef __attribute__((ext_vector_type(4))) float f32x4;
typedef __attribute__((ext_vector_type(16))) float f32x16;
typedef __attribute__((ext_vector_type(4))) unsigned int u32x4;
typedef __attribute__((ext_vector_type(4))) unsigned short u16x4;
typedef unsigned int u32;
typedef unsigned short u16;

#define DEV static __device__ __forceinline__

DEV u16 f2bf(float f) {
  union { float f; u32 u; } c; c.f = f;
  u32 r = (c.u + 0x7fffu + ((c.u >> 16) & 1u)) >> 16;
  return (u16)r;
}
DEV float bf2f(u16 v) {
  union { u32 u; float f; } c; c.u = ((u32)v) << 16;
  return c.f;
}
DEV short8 pack8(float4 a, float4 b) {
  short8 r;
  r[0]=(short)f2bf(a.x); r[1]=(short)f2bf(a.y); r[2]=(short)f2bf(a.z); r[3]=(short)f2bf(a.w);
  r[4]=(short)f2bf(b.x); r[5]=(short)f2bf(b.y); r[6]=(short)f2bf(b.z); r[7]=(short)f2bf(b.w);
  return r;
}
DEV u32 cvtpk(float lo, float hi) {  // packed bf16 pair, RTNE
  u32 r;
  asm("v_cvt_pk_bf16_f32 %0, %1, %2" : "=v"(r) : "v"(lo), "v"(hi));
  return r;
}

// fast exp2: single v_exp_f32 (library exp2f carries range-check overhead)
#if __has_builtin(__builtin_amdgcn_exp2f)
DEV float fexp2(float x) { return __builtin_amdgcn_exp2f(x); }
#else
DEV float fexp2(float x) { return exp2f(x); }
#endif

DEV void glds16(const void* g, void* l) {
  __builtin_amdgcn_global_load_lds((const __attribute__((address_space(1))) u32*)g,
                                   (__attribute__((address_space(3))) u32*)l, 16, 0, 0);
}

DEV f32x16 mfma32(short8 a, short8 b, f32x16 c) {
  return __builtin_amdgcn_mfma_f32_32x32x16_bf16(a, b, c, 0, 0, 0);
}

constexpr int CDIM = 1024, TT = 2048, NH = 16, DK = 64;
// Q pre-scale: 1/sqrt(64) * log2(e)  (softmax runs in exp2 domain)
#define QSC 0.1803368801111601f

// ---------------- fp32 -> bf16 conversion, block-partitioned ---------------
__global__ void conv_bf16b(const float* __restrict__ X, const float* __restrict__ W1,
                           const float* __restrict__ W2, u16* __restrict__ Xb,
                           u16* __restrict__ W1b, u16* __restrict__ W2b) {
  const int bid = blockIdx.x;
  const float* s; u16* d; long base;
  if (bid < 1024)      { s = X;  d = Xb;  base = (long)bid * 1024; }
  else if (bid < 1408) { s = W1; d = W1b; base = (long)(bid - 1024) * 1024; }
  else                 { s = W2; d = W2b; base = (long)(bid - 1408) * 1024; }
#pragma unroll
  for (int i = 0; i < 4; ++i) {
    const long j = base + i * 256 + threadIdx.x;
    float4 a = ((const float4*)s)[2 * j];
    float4 b = ((const float4*)s)[2 * j + 1];
    ((short8*)d)[j] = pack8(a, b);
  }
}

// ---------------- QKV GEMM v9 (r18 winner): 128x128, 4 waves, swizzled ------
__global__ void qkv_gemm9(const u16* __restrict__ A, const u16* __restrict__ B,
                          const float* __restrict__ bias, u16* __restrict__ Qb,
                          u16* __restrict__ Kb, u16* __restrict__ VTb) {
  __shared__ u16 As[128][64];
  __shared__ u16 Bs[128][64];
  const int tid = threadIdx.x, lane = tid & 63, wv = tid >> 6;
  const int wr = wv >> 1, wc = wv & 1, lo = lane & 15, lg = lane >> 4;
  const int m0 = blockIdx.x * 128, n0 = blockIdx.y * 128;
  const int rin = lane >> 3, blk = lane & 7;
  const int r7 = lo & 7;

  f32x4 acc[4][4];
  const f32x4 fz = {0.f, 0.f, 0.f, 0.f};
#pragma unroll
  for (int i = 0; i < 4; ++i)
#pragma unroll
    for (int j = 0; j < 4; ++j) acc[i][j] = fz;

  const u16* ga = A + (size_t)(m0 + 32 * wv + rin) * CDIM + (blk ^ rin) * 8;
  const u16* gb = B + (size_t)(n0 + 32 * wv + rin) * CDIM + (blk ^ rin) * 8;

  for (int k0 = 0; k0 < CDIM; k0 += 64) {
#pragma unroll
    for (int i = 0; i < 4; ++i) glds16(ga + k0 + (size_t)(8 * i) * CDIM, &As[32 * wv + 8 * i][0]);
#pragma unroll
    for (int i = 0; i < 4; ++i) glds16(gb + k0 + (size_t)(8 * i) * CDIM, &Bs[32 * wv + 8 * i][0]);
    __syncthreads();
#pragma unroll
    for (int kk = 0; kk < 2; ++kk) {
      short8 af[4], bf[4];
#pragma unroll
      for (int mi = 0; mi < 4; ++mi)
        af[mi] = *(const short8*)&As[wr * 64 + mi * 16 + lo][(((kk * 4 + lg) ^ r7) * 8)];
#pragma unroll
      for (int ni = 0; ni < 4; ++ni)
        bf[ni] = *(const short8*)&Bs[wc * 64 + ni * 16 + lo][(((kk * 4 + lg) ^ r7) * 8)];
#pragma unroll
      for (int mi = 0; mi < 4; ++mi)
#pragma unroll
        for (int ni = 0; ni < 4; ++ni)
          acc[mi][ni] = __builtin_amdgcn_mfma_f32_16x16x32_bf16(af[mi], bf[ni], acc[mi][ni], 0, 0, 0);
    }
    __syncthreads();
  }

  // ---- scatter epilogue ----
#pragma unroll
  for (int ni = 0; ni < 4; ++ni) {
    const int o = n0 + wc * 64 + ni * 16 + lo;
    const float bv = bias[o];
    const int h = o / 192, rem = o - h * 192, which = rem >> 6, d = rem & 63;
#pragma unroll
    for (int mi = 0; mi < 4; ++mi) {
      const int mb = m0 + wr * 64 + mi * 16 + lg * 4;
      const int bb = mb >> 11, t0 = mb & 2047;
      const int bh = bb * NH + h;
      if (which == 2) {
        u16x4 pk;
#pragma unroll
        for (int r = 0; r < 4; ++r) pk[r] = f2bf(acc[mi][ni][r] + bv);
        *(u16x4*)&VTb[((size_t)bh * DK + d) * TT + t0] = pk;
      } else if (which == 1) {
#pragma unroll
        for (int r = 0; r < 4; ++r)
          Kb[((size_t)bh * TT + t0 + r) * DK + d] = f2bf(acc[mi][ni][r] + bv);
      } else {
#pragma unroll
        for (int r = 0; r < 4; ++r)
          Qb[((size_t)bh * TT + t0 + r) * DK + d] = f2bf((acc[mi][ni][r] + bv) * QSC);
      }
    }
  }
}

// ---------------- Flash attention v13: 256-q blocks (8 waves), 2x staging
// amortization. Block = (chunk-pair cj, parity sp, bh), chunks {cj, 7-cj}:
// 18 staged tiles/block uniform; 512 blocks x 8 waves = same waves/CU as v10
// but half the staging traffic + half the barriers per unit compute.
__global__ void __launch_bounds__(512, 4)
attn13(const u16* __restrict__ Qb, const u16* __restrict__ Kb,
       const u16* __restrict__ VTb, u16* __restrict__ PA, u16* __restrict__ PB,
       float* __restrict__ ML) {
  __shared__ u16 Kls[2][64][64];
  __shared__ u16 Vls[2][64][64];
  const int tid = threadIdx.x, lane = tid & 63, wv = tid >> 6;  // wv 0..7
  const int lq = lane & 31, h = lane >> 5;
  const int id = blockIdx.x;
  const int w = (id & 7) * 64 + (id >> 3);   // XCD-chunked: 8 bh per XCD
  const int bh = w >> 3;
  const int cj = w & 3;                      // chunk-pair index 0..3
  const int sp = (w >> 2) & 1;               // kv parity
  const int bb = bh >> 4, head = bh & 15;
  const u16* Qp = Qb + (size_t)bh * TT * DK;
  const u16* Kp = Kb + (size_t)bh * TT * DK;
  const u16* Vp = VTb + (size_t)bh * DK * TT;
  const int rin = lane >> 3, blk = lane & 7;
  u16* PO = sp ? PB : PA;

  // each wave stages 8 K-rows + 8 V-rows (one glds16 each)
  const u16* kga = Kp + (size_t)(wv * 8 + rin) * DK + (blk ^ rin) * 8;
  const u16* vga = Vp + (size_t)(wv * 8 + rin) * TT + (blk ^ rin) * 8;
  u16* kls0 = &Kls[0][wv * 8][0];
  u16* vls0 = &Vls[0][wv * 8][0];
  const int lds_half = 64 * 64;

#define STAGE13(bufi, kvt_)                                                 \
  {                                                                         \
    const int o_ = (bufi) * lds_half;                                       \
    glds16(kga + (size_t)(kvt_) * 4096, kls0 + o_);                         \
    glds16(vga + (size_t)(kvt_) * 64, vls0 + o_);                           \
  }

  for (int pi = 0; pi < 2; ++pi) {
    const int chunk = pi ? (7 - cj) : cj;        // chunk covers qtiles {2c, 2c+1}
    const int q0w = chunk * 256 + wv * 32;
    const int qrow = q0w + lq;

    short8 qw[4];
#pragma unroll
    for (int kk = 0; kk < 4; ++kk)
      qw[kk] = *(const short8*)&Qp[(size_t)qrow * DK + kk * 16 + h * 8];

    f32x16 oa0, oa1;
#pragma unroll
    for (int r = 0; r < 16; ++r) { oa0[r] = 0.f; oa1[r] = 0.f; }
    float l_s = 0.f;

    const int nt = 4 * chunk + 4;               // covers qtile 2c+1
    STAGE13(0, sp);
    __syncthreads();
    int buf = 0;
    for (int kvt = sp; kvt < nt; kvt += 2) {
      const int kv0 = kvt * 64;
      if (kvt + 2 < nt) STAGE13(buf ^ 1, kvt + 2);
      if (kv0 <= q0w + 31) {
        f32x16 s0, s1;
#pragma unroll
        for (int r = 0; r < 16; ++r) { s0[r] = 0.f; s1[r] = 0.f; }
        __builtin_amdgcn_s_setprio(1);
#pragma unroll
        for (int kk = 0; kk < 4; ++kk) {
          const short8 kf0 = *(const short8*)&Kls[buf][lq][(((2 * kk + h) ^ (lq & 7)) * 8)];
          const short8 kf1 = *(const short8*)&Kls[buf][32 + lq][(((2 * kk + h) ^ (lq & 7)) * 8)];
          s0 = mfma32(kf0, qw[kk], s0);
          s1 = mfma32(kf1, qw[kk], s1);
        }
        __builtin_amdgcn_s_setprio(0);
        const bool diag = (kv0 + 63 > q0w);
        if (diag) {
          const int lim = qrow - kv0 - 4 * h;
#pragma unroll
          for (int r = 0; r < 16; ++r) {
            const int kl = (r & 3) + 8 * (r >> 2);
            s0[r] = (kl <= lim) ? s0[r] : -1e30f;
            s1[r] = (kl + 32 <= lim) ? s1[r] : -1e30f;
          }
        }
        float rsa = 0.f, rsb = 0.f, rsc = 0.f, rsd = 0.f;
#pragma unroll
        for (int r = 0; r < 16; r += 4) {
          const float a0 = fexp2(s0[r]),     a1 = fexp2(s1[r]);
          const float b0 = fexp2(s0[r + 1]), b1 = fexp2(s1[r + 1]);
          const float c0 = fexp2(s0[r + 2]), c1 = fexp2(s1[r + 2]);
          const float d0 = fexp2(s0[r + 3]), d1 = fexp2(s1[r + 3]);
          s0[r] = a0; s1[r] = a1; s0[r + 1] = b0; s1[r + 1] = b1;
          s0[r + 2] = c0; s1[r + 2] = c1; s0[r + 3] = d0; s1[r + 3] = d1;
          rsa += a0 + a1; rsb += b0 + b1; rsc += c0 + c1; rsd += d0 + d1;
        }
        float rs = (rsa + rsb) + (rsc + rsd);
        rs += __shfl_xor(rs, 32);
        l_s += rs;
#pragma unroll
        for (int s = 0; s < 2; ++s) {
          u32 C[8];
#pragma unroll
          for (int j = 0; j < 8; ++j)
            C[j] = s ? cvtpk(s1[2 * j], s1[2 * j + 1]) : cvtpk(s0[2 * j], s0[2 * j + 1]);
#pragma unroll
          for (int b = 0; b < 2; ++b) {
            const int o = 4 * b;
            const u32 D1 = h ? C[o + 0] : C[o + 2];
            const u32 D2 = h ? C[o + 1] : C[o + 3];
            const u32 R1 = __shfl_xor(D1, 32);
            const u32 R2 = __shfl_xor(D2, 32);
            union { u32x4 w; short8 s8; } pa;
            pa.w[0] = h ? R1 : C[o + 0];
            pa.w[1] = h ? R2 : C[o + 1];
            pa.w[2] = h ? C[o + 2] : R1;
            pa.w[3] = h ? C[o + 3] : R2;
            const int ks = 2 * s + b;
            const short8 vb0 = *(const short8*)&Vls[buf][lq][(((2 * ks + h) ^ (lq & 7)) * 8)];
            const short8 vb1 = *(const short8*)&Vls[buf][32 + lq][(((2 * ks + h) ^ (lq & 7)) * 8)];
            __builtin_amdgcn_s_setprio(1);
            oa0 = mfma32(pa.s8, vb0, oa0);
            oa1 = mfma32(pa.s8, vb1, oa1);
            __builtin_amdgcn_s_setprio(0);
          }
        }
      }
      __syncthreads();
      buf ^= 1;
    }

#pragma unroll
    for (int r = 0; r < 16; ++r) {
      const int t = q0w + (r & 3) + 8 * (r >> 2) + 4 * h;
      const size_t rowb = ((size_t)(bb * TT + t)) * CDIM + head * DK;
      PO[rowb + lq] = f2bf(oa0[r]);
      PO[rowb + 32 + lq] = f2bf(oa1[r]);
    }
    if (h == 0) ML[((size_t)(sp * 64 + bh) << 11) + qrow] = l_s;
    __syncthreads();
  }
#undef STAGE13
}

// ---------------- merge of the two kv-parity partials ----------------------
__global__ void attn_merge(const u16* PA, const u16* PB,
                           const float* __restrict__ ML, u16* Ctx) {
  const int row = blockIdx.x;  // b*2048 + t
  const int b = row >> 11, t = row & 2047;
  const int c = threadIdx.x * 4;
  const int head = c >> 6;
  const int bh = b * NH + head;
  const float lA = ML[((size_t)bh << 11) + t];
  const float lB = ML[((size_t)(64 + bh) << 11) + t];
  const float il = 1.0f / (lA + lB);
  const size_t idx = ((size_t)row) * CDIM + c;
  u16x4 pa = *(const u16x4*)&PA[idx];
  u16x4 pb = *(const u16x4*)&PB[idx];
  u16x4 o;
#pragma unroll
  for (int e = 0; e < 4; ++e) o[e] = f2bf((bf2f(pa[e]) + bf2f(pb[e])) * il);
  *(u16x4*)&Ctx[idx] = o;
}

// ---------------- Output GEMM v4: m97 structure + proven LDS swizzle --------
__global__ void out_gemm4(const u16* __restrict__ A, const u16* __restrict__ B,
                          const float* __restrict__ bias, float* __restrict__ Out) {
  __shared__ u16 As[128][64];
  __shared__ u16 Bs[128][64];
  const int tid = threadIdx.x, lane = tid & 63, wv = tid >> 6;
  const int wr = wv >> 1, wc = wv & 1, lo = lane & 15, lg = lane >> 4;
  const int m0 = blockIdx.x * 128, n0 = blockIdx.y * 128;
  const int rin = lane >> 3, blk = lane & 7;
  const int r7 = lo & 7;

  f32x4 acc[4][4];
  const f32x4 fz = {0.f, 0.f, 0.f, 0.f};
#pragma unroll
  for (int i = 0; i < 4; ++i)
#pragma unroll
    for (int j = 0; j < 4; ++j) acc[i][j] = fz;

  const u16* ga = A + (size_t)(m0 + 32 * wv + rin) * CDIM + (blk ^ rin) * 8;
  const u16* gb = B + (size_t)(n0 + 32 * wv + rin) * CDIM + (blk ^ rin) * 8;

  for (int k0 = 0; k0 < CDIM; k0 += 64) {
#pragma unroll
    for (int i = 0; i < 4; ++i) glds16(ga + k0 + (size_t)(8 * i) * CDIM, &As[32 * wv + 8 * i][0]);
#pragma unroll
    for (int i = 0; i < 4; ++i) glds16(gb + k0 + (size_t)(8 * i) * CDIM, &Bs[32 * wv + 8 * i][0]);
    __syncthreads();
#pragma unroll
    for (int kk = 0; kk < 2; ++kk) {
      short8 af[4], bf[4];
#pragma unroll
      for (int mi = 0; mi < 4; ++mi)
        af[mi] = *(const short8*)&As[wr * 64 + mi * 16 + lo][(((kk * 4 + lg) ^ r7) * 8)];
#pragma unroll
      for (int ni = 0; ni < 4; ++ni)
        bf[ni] = *(const short8*)&Bs[wc * 64 + ni * 16 + lo][(((kk * 4 + lg) ^ r7) * 8)];
#pragma unroll
      for (int mi = 0; mi < 4; ++mi)
#pragma unroll
        for (int ni = 0; ni < 4; ++ni)
          acc[mi][ni] = __builtin_amdgcn_mfma_f32_16x16x32_bf16(af[mi], bf[ni], acc[mi][ni], 0, 0, 0);
    }
    __syncthreads();
  }

#pragma unroll
  for (int ni = 0; ni < 4; ++ni) {
    const int o = n0 + wc * 64 + ni * 16 + lo;
    const float bv = bias[o];
#pragma unroll
    for (int mi = 0; mi < 4; ++mi)
#pragma unroll
      for (int r = 0; r < 4; ++r)
        Out[(size_t)(m0 + wr * 64 + mi * 16 + lg * 4 + r) * CDIM + o] = acc[mi][ni][r] + bv;
  }
}

extern "C" void kernel_launch(void* const* d_in, const int* in_sizes, int n_in,
                              void* d_out, int out_size, void* d_ws, size_t ws_size,
                              hipStream_t stream) {
  const float* X = (const float*)d_in[0];
  const float* Wqkv = (const float*)d_in[1];
  const float* bqkv = (const float*)d_in[2];
  const float* Wout = (const float*)d_in[3];
  const float* bout = (const float*)d_in[4];
  float* Out = (float*)d_out;

  u16* Xb  = (u16*)d_ws;              // 8,388,608 u16 (reused as PB after qkv)
  u16* W1b = Xb + 8388608;            // 3,145,728 u16 (reused as ML after qkv)
  u16* W2b = W1b + 3145728;           // 1,048,576
  u16* Qb  = W2b + 1048576;           // 8,388,608 (pre-scaled by QSC)
  u16* Kb  = Qb + 8388608;            // 8,388,608
  u16* VTb = Kb + 8388608;            // 8,388,608 (transposed: [bh][d][t])
  u16* Ctx = VTb + 8388608;           // 8,388,608 (PA partial, then merged in-place)

  conv_bf16b<<<1536, 256, 0, stream>>>(X, Wqkv, Wout, Xb, W1b, W2b);
  qkv_gemm9<<<dim3(64, 24), 256, 0, stream>>>(Xb, W1b, bqkv, Qb, Kb, VTb);
  attn13<<<dim3(512), 512, 0, stream>>>(Qb, Kb, VTb, Ctx, Xb, (float*)W1b);
  attn_merge<<<8192, 256, 0, stream>>>(Ctx, Xb, (const float*)W1b, Ctx);
  out_gemm4<<<dim3(64, 8), 256, 0, stream>>>(Ctx, W2b, bout, Out);
}